// Round 11
// baseline (582.810 us; speedup 1.0000x reference)
//
#include <hip/hip_runtime.h>
#include <math.h>
#include <float.h>

#define VOCAB    32000
#define NT       1024
#define NWAVES   (NT / 64)
#define ACC_NT   256
#define RPB      4         // rows per block, swept as ONE contiguous 512KB window
#define CPR      125       // 1KB chunks (64 float4) per row
#define NCHUNK   8000      // float4 per row
#define CAPG     512       // per-row candidate buffer; E=228, +19 sigma
#define CAPF     1024      // fallback rescan buffer (single row at a time)
#define KMAX     64
#define KREF     24.0f
#define THETA0   14.0f
#define LOG2E    1.4426950408889634f
#define THT      ((THETA0 - KREF) * LOG2E)
#define FBDELTA  (12.0f * LOG2E)

typedef float vf4 __attribute__((ext_vector_type(4)));

// R11: stream-count x concurrency probe -- the untested matrix cell.
// Evidence: R5 (2048 windows, full concurrency) 1.67 TB/s; R6 (512 windows, 1/4
// concurrency) 2.2 GB/s/stream (+2.5x per-stream) but 1.13 TB/s total; R7 (8192
// huge-stride wave streams) 1.10 TB/s. R10's spill variant moved +30% bytes in
// the SAME time -> not a service-bandwidth ceiling; pattern-bound.
// This kernel: 512 blocks x NT=1024, each sweeping 4 consecutive rows (512KB) in
// strict address order -- instantaneous footprint = 512 contiguous 16KB windows
// at FULL machine concurrency. Per-row sums in wave-uniform-branch accumulators
// (chunks never span rows); candidates to per-row LDS buffers (exact v/T values);
// rank/top-p/Gumbel verbatim from the verified R5 kernel -> skept/conf bitwise.
// NO sched_barrier pinning (R10 lesson: causes scratch spills).

#define PROCESS_R(v, c)                                                             \
    {                                                                               \
        const int rl = (c) / CPR;                                                   \
        float t0 = fmaf((v).x, a, b);                                               \
        float t1 = fmaf((v).y, a, b);                                               \
        float t2 = fmaf((v).z, a, b);                                               \
        float t3 = fmaf((v).w, a, b);                                               \
        float e0 = exp2f(t0), e1 = exp2f(t1), e2 = exp2f(t2), e3 = exp2f(t3);       \
        float tmc = fmaxf(fmaxf(t0, t1), fmaxf(t2, t3));                            \
        if (rl == 0)      { sA0 += e0; sB0 += e1; sA0 += e2; sB0 += e3; tm0 = fmaxf(tm0, tmc); } \
        else if (rl == 1) { sA1 += e0; sB1 += e1; sA1 += e2; sB1 += e3; tm1 = fmaxf(tm1, tmc); } \
        else if (rl == 2) { sA2 += e0; sB2 += e1; sA2 += e2; sB2 += e3; tm2 = fmaxf(tm2, tmc); } \
        else              { sA3 += e0; sB3 += e1; sA3 += e2; sB3 += e3; tm3 = fmaxf(tm3, tmc); } \
        const int bi = ((c) - rl * CPR) * 256 + (lane << 2);                        \
        if (t0 > THT) { int p = atomicAdd(&s_cnt[rl], 1); if (p < CAPG) { s_val[rl*CAPG+p] = (v).x / T; s_idx[rl*CAPG+p] = bi;     } } \
        if (t1 > THT) { int p = atomicAdd(&s_cnt[rl], 1); if (p < CAPG) { s_val[rl*CAPG+p] = (v).y / T; s_idx[rl*CAPG+p] = bi + 1; } } \
        if (t2 > THT) { int p = atomicAdd(&s_cnt[rl], 1); if (p < CAPG) { s_val[rl*CAPG+p] = (v).z / T; s_idx[rl*CAPG+p] = bi + 2; } } \
        if (t3 > THT) { int p = atomicAdd(&s_cnt[rl], 1); if (p < CAPG) { s_val[rl*CAPG+p] = (v).w / T; s_idx[rl*CAPG+p] = bi + 3; } } \
    }

__global__ __launch_bounds__(NT, 8) void dream_sweep4_kernel(
    const float* __restrict__ logits,
    const float* __restrict__ gumbel,
    const float* __restrict__ tempP,
    const float* __restrict__ toppP,
    const int*   __restrict__ topkP,
    float* __restrict__ out_conf,
    float* __restrict__ out_x0,
    float* __restrict__ out_iconf,
    int nRows)
{
    const int tid  = threadIdx.x;
    const int lane = tid & 63;
    const int wid  = tid >> 6;
    const int r0   = blockIdx.x * RPB;
    const int nr   = min(RPB, nRows - r0);
    const int nc   = nr * CPR;                       // chunks in this block's window
    const vf4* l4  = (const vf4*)logits + (size_t)r0 * NCHUNK;
    const float T  = tempP[0];
    const float a  = (1.0f / T) * LOG2E;
    const float b  = -(KREF * LOG2E);

    __shared__ float s_val[RPB * CAPG];
    __shared__ int   s_idx[RPB * CAPG];
    __shared__ int   s_cnt[RPB];
    __shared__ float fb_val[CAPF];
    __shared__ int   fb_idx[CAPF];
    __shared__ int   fb_cnt;
    __shared__ float wsum[RPB * NWAVES], wmax[RPB * NWAVES];
    __shared__ float sh_S[RPB], sh_m[RPB];
    __shared__ float so_val[KMAX];
    __shared__ int   so_idx[KMAX];
    __shared__ int   sh_nk;
    __shared__ float sh_skept;

    if (tid < RPB) s_cnt[tid] = 0;
    __syncthreads();

    // ---- address-ordered sweep: wave w takes chunks c = w + 16k ----
    float sA0 = 0, sB0 = 0, sA1 = 0, sB1 = 0, sA2 = 0, sB2 = 0, sA3 = 0, sB3 = 0;
    float tm0 = -FLT_MAX, tm1 = -FLT_MAX, tm2 = -FLT_MAX, tm3 = -FLT_MAX;

    int c = wid;
    for (; c + 112 < nc; c += 128) {                 // batches of 8 chunks
        vf4 g0 = __builtin_nontemporal_load(&l4[(size_t)(c       ) * 64 + lane]);
        vf4 g1 = __builtin_nontemporal_load(&l4[(size_t)(c +  16 ) * 64 + lane]);
        vf4 g2 = __builtin_nontemporal_load(&l4[(size_t)(c +  32 ) * 64 + lane]);
        vf4 g3 = __builtin_nontemporal_load(&l4[(size_t)(c +  48 ) * 64 + lane]);
        vf4 g4 = __builtin_nontemporal_load(&l4[(size_t)(c +  64 ) * 64 + lane]);
        vf4 g5 = __builtin_nontemporal_load(&l4[(size_t)(c +  80 ) * 64 + lane]);
        vf4 g6 = __builtin_nontemporal_load(&l4[(size_t)(c +  96 ) * 64 + lane]);
        vf4 g7 = __builtin_nontemporal_load(&l4[(size_t)(c + 112 ) * 64 + lane]);
        PROCESS_R(g0, c);
        PROCESS_R(g1, c + 16);
        PROCESS_R(g2, c + 32);
        PROCESS_R(g3, c + 48);
        PROCESS_R(g4, c + 64);
        PROCESS_R(g5, c + 80);
        PROCESS_R(g6, c + 96);
        PROCESS_R(g7, c + 112);
    }
    for (; c + 48 < nc; c += 64) {                   // batch of 4
        vf4 g0 = __builtin_nontemporal_load(&l4[(size_t)(c      ) * 64 + lane]);
        vf4 g1 = __builtin_nontemporal_load(&l4[(size_t)(c + 16 ) * 64 + lane]);
        vf4 g2 = __builtin_nontemporal_load(&l4[(size_t)(c + 32 ) * 64 + lane]);
        vf4 g3 = __builtin_nontemporal_load(&l4[(size_t)(c + 48 ) * 64 + lane]);
        PROCESS_R(g0, c);
        PROCESS_R(g1, c + 16);
        PROCESS_R(g2, c + 32);
        PROCESS_R(g3, c + 48);
    }
    for (; c < nc; c += 16) {                        // singles (<=3 per wave)
        vf4 g0 = __builtin_nontemporal_load(&l4[(size_t)c * 64 + lane]);
        PROCESS_R(g0, c);
    }

    // ---- wave reduce (4 rows), then fixed-order cross-wave combine ----
    float s0 = sA0 + sB0, s1 = sA1 + sB1, s2 = sA2 + sB2, s3 = sA3 + sB3;
    #pragma unroll
    for (int o = 32; o > 0; o >>= 1) {
        s0 += __shfl_down(s0, o, 64); tm0 = fmaxf(tm0, __shfl_down(tm0, o, 64));
        s1 += __shfl_down(s1, o, 64); tm1 = fmaxf(tm1, __shfl_down(tm1, o, 64));
        s2 += __shfl_down(s2, o, 64); tm2 = fmaxf(tm2, __shfl_down(tm2, o, 64));
        s3 += __shfl_down(s3, o, 64); tm3 = fmaxf(tm3, __shfl_down(tm3, o, 64));
    }
    if (lane == 0) {
        wsum[0 * NWAVES + wid] = s0; wmax[0 * NWAVES + wid] = tm0;
        wsum[1 * NWAVES + wid] = s1; wmax[1 * NWAVES + wid] = tm1;
        wsum[2 * NWAVES + wid] = s2; wmax[2 * NWAVES + wid] = tm2;
        wsum[3 * NWAVES + wid] = s3; wmax[3 * NWAVES + wid] = tm3;
    }
    __syncthreads();
    if (tid < RPB) {
        float S = 0.0f, M = -FLT_MAX;
        #pragma unroll
        for (int w = 0; w < NWAVES; ++w) {
            S += wsum[tid * NWAVES + w];
            M = fmaxf(M, wmax[tid * NWAVES + w]);
        }
        sh_S[tid] = S; sh_m[tid] = M;
    }
    __syncthreads();

    // ---- per-row epilogue (sequential; verbatim R5 logic) ----
    for (int r = 0; r < nr; ++r) {
        const size_t base = (size_t)(r0 + r) * VOCAB;
        int C = min(s_cnt[r], CAPG);
        const float* rv = &s_val[r * CAPG];
        const int*   ri = &s_idx[r * CAPG];

        // rare fallback: fixed theta missed -- rescan this row with adaptive theta
        if (C < KMAX) {
            if (tid == 0) fb_cnt = 0;
            __syncthreads();
            const float th2t = sh_m[r] - FBDELTA;
            const vf4* lr = (const vf4*)(logits + base);
            for (int j = tid; j < NCHUNK; j += NT) {
                vf4 v = __builtin_nontemporal_load(&lr[j]);
                float t0 = fmaf(v.x, a, b);
                float t1 = fmaf(v.y, a, b);
                float t2 = fmaf(v.z, a, b);
                float t3 = fmaf(v.w, a, b);
                int bi = j * 4;
                if (t0 > th2t) { int p = atomicAdd(&fb_cnt, 1); if (p < CAPF) { fb_val[p] = v.x / T; fb_idx[p] = bi;     } }
                if (t1 > th2t) { int p = atomicAdd(&fb_cnt, 1); if (p < CAPF) { fb_val[p] = v.y / T; fb_idx[p] = bi + 1; } }
                if (t2 > th2t) { int p = atomicAdd(&fb_cnt, 1); if (p < CAPF) { fb_val[p] = v.z / T; fb_idx[p] = bi + 2; } }
                if (t3 > th2t) { int p = atomicAdd(&fb_cnt, 1); if (p < CAPF) { fb_val[p] = v.w / T; fb_idx[p] = bi + 3; } }
            }
            __syncthreads();
            C = min(fb_cnt, CAPF);
            rv = fb_val; ri = fb_idx;
        }

        // rank candidates on exact x (stable: value desc, index asc); keep top-KMAX
        for (int cc = tid; cc < C; cc += NT) {
            float vc = rv[cc]; int ic = ri[cc];
            int rk = 0;
            #pragma unroll 4
            for (int j = 0; j < C; ++j) {
                float vj = rv[j];
                if (vj > vc || (vj == vc && ri[j] < ic)) rk++;
            }
            if (rk < KMAX) { so_val[rk] = vc; so_idx[rk] = ic; }
        }
        __syncthreads();

        // top-p prefix walk + top-k cap; replicate reference addition order
        if (tid == 0) {
            int k = topkP[0]; if (k > KMAX) k = KMAX; if (k < 1) k = 1;
            const float topp = toppP[0];
            const int lim = min(C, k);
            float cum = 0.0f;
            float skept = 0.0f;
            int nk = 0;
            for (int j = 0; j < lim; ++j) {
                if (cum > topp) break;
                float e = exp2f(fmaf(so_val[j], LOG2E, b));
                cum += e / sh_S[r];
                skept += e;
                nk++;
            }
            sh_nk = nk;
            sh_skept = skept;
        }
        __syncthreads();
        const int nk = sh_nk;
        const float skept = sh_skept;

        // Gumbel argmax over kept tokens (wave 0; first-index tie-break)
        if (wid == 0) {
            float bv = -FLT_MAX; int bi = 0x7FFFFFFF; float bx = 0.0f;
            if (lane < nk) {
                int gi = so_idx[lane];
                bx = rv == fb_val ? so_val[lane] : so_val[lane];   // exact x either way
                bx = so_val[lane];
                bv = bx + gumbel[base + gi];
                bi = gi;
            }
            #pragma unroll
            for (int o = 32; o > 0; o >>= 1) {
                float ov = __shfl_down(bv, o, 64);
                int   oi = __shfl_down(bi, o, 64);
                float ox = __shfl_down(bx, o, 64);
                if (ov > bv || (ov == bv && oi < bi)) { bv = ov; bi = oi; bx = ox; }
            }
            if (lane == 0) {
                float eb = exp2f(fmaf(bx, LOG2E, b));
                float confv = eb / skept;
                out_conf[r0 + r]  = confv;
                out_x0[r0 + r]    = (float)bi;
                out_iconf[r0 + r] = confv;
            }
        }
        __syncthreads();   // so_val/fb reuse safe for next row
    }
}

// Global accept step: any(conf > thr) ? per-row high : one-hot at argmax(conf)
__global__ __launch_bounds__(ACC_NT) void accept_kernel(
    const float* __restrict__ conf,
    const float* __restrict__ thrP,
    float* __restrict__ acc_out,
    int N)
{
    __shared__ float rv[ACC_NT];
    __shared__ int   ri[ACC_NT];
    __shared__ int   ra[ACC_NT];
    const int tid = threadIdx.x;
    const float thr = thrP[0];

    float bv = -FLT_MAX; int bi = 0x7FFFFFFF; int any = 0;
    for (int i = tid; i < N; i += ACC_NT) {
        float v = conf[i];
        if (v > thr) any = 1;
        if (v > bv) { bv = v; bi = i; }
    }
    rv[tid] = bv; ri[tid] = bi; ra[tid] = any;
    __syncthreads();
    #pragma unroll
    for (int s = ACC_NT / 2; s > 0; s >>= 1) {
        if (tid < s) {
            float ov = rv[tid + s]; int oi = ri[tid + s];
            if (ov > rv[tid] || (ov == rv[tid] && oi < ri[tid])) {
                rv[tid] = ov; ri[tid] = oi;
            }
            ra[tid] |= ra[tid + s];
        }
        __syncthreads();
    }
    const int anyHigh = ra[0];
    const int amax = ri[0];
    for (int i = tid; i < N; i += ACC_NT) {
        float a;
        if (anyHigh) a = (conf[i] > thr) ? 1.0f : 0.0f;
        else         a = (i == amax) ? 1.0f : 0.0f;
        acc_out[i] = a;
    }
}

extern "C" void kernel_launch(void* const* d_in, const int* in_sizes, int n_in,
                              void* d_out, int out_size, void* d_ws, size_t ws_size,
                              hipStream_t stream)
{
    const float* logits = (const float*)d_in[0];
    const float* gumbel = (const float*)d_in[1];
    const float* tempP  = (const float*)d_in[2];
    const float* toppP  = (const float*)d_in[3];
    const int*   topkP  = (const int*)d_in[4];
    const float* thrP   = (const float*)d_in[5];
    float* out = (float*)d_out;
    const int N = in_sizes[0] / VOCAB;
    const int nBlocks = (N + RPB - 1) / RPB;

    dream_sweep4_kernel<<<nBlocks, NT, 0, stream>>>(
        logits, gumbel, tempP, toppP, topkP,
        out /*confidence*/, out + N /*x0*/, out + 2 * N /*initial_confidence*/, N);

    accept_kernel<<<1, ACC_NT, 0, stream>>>(
        out, thrP, out + 3 * N /*accepted*/, N);
}

// Round 12
// 505.618 us; speedup vs baseline: 1.1527x; 1.1527x over previous
//
#include <hip/hip_runtime.h>
#include <math.h>
#include <float.h>

#define VOCAB    32000
#define NT       256
#define NWAVES   (NT / 64)
#define CAP      1024    // candidate buffer; E[count]=228 at THETA0
#define KMAX     64      // >= top_k (50)
#define KREF     24.0f
#define THETA0   14.0f
#define LOG2E    1.4426950408889634f
#define THT      ((THETA0 - KREF) * LOG2E)
#define FBDELTA  (12.0f * LOG2E)
#define NCHUNK   (VOCAB / 4)   // 8000 float4 per row
#define QUART    2048          // float4 per wave-quarter (w=3 gets 1856)

typedef float vf4 __attribute__((ext_vector_type(4)));

// R12: 8192 contiguous wave-streams. Stream-count scaling measured so far:
// 512 streams -> ~2.3 GB/s/stream (R6/R11), 2048 -> 0.82 (R5); aggregate rises
// sublinearly with count (DRAM bank-level parallelism). The 8192-stream cell was
// never cleanly tested: R7's wave-streams were non-contiguous (8MB hops) with
// shuffle/lgkm serialization in the hot loop. This kernel = R5 verbatim (nt,
// 8-deep source batches, launch_bounds(256,8), clean hot loop) except each WAVE
// owns a contiguous quarter of its row: w<3 -> 32x1KB chunks, w=3 -> 29.
// Register structure unchanged -> no spill (check: VGPR<=48, WRITE~0.2MB).
// Per-thread summation order changes; this ULP class passed absmax 0.0 in
// R7/R11. Candidate values remain exact v/T; rank/top-p/Gumbel verbatim.

#define PROCESS(v, jj)                                                              \
    {                                                                               \
        float t0 = fmaf((v).x, a, b);                                               \
        float t1 = fmaf((v).y, a, b);                                               \
        float t2 = fmaf((v).z, a, b);                                               \
        float t3 = fmaf((v).w, a, b);                                               \
        sA += exp2f(t0);                                                            \
        sB += exp2f(t1);                                                            \
        sA += exp2f(t2);                                                            \
        sB += exp2f(t3);                                                            \
        tmax = fmaxf(tmax, fmaxf(fmaxf(t0, t1), fmaxf(t2, t3)));                    \
        int bi = (jj) * 4;                                                          \
        if (t0 > THT) { int p = atomicAdd(&s_cnt, 1); if (p < CAP) { s_val[p] = (v).x / T; s_idx[p] = bi;     } } \
        if (t1 > THT) { int p = atomicAdd(&s_cnt, 1); if (p < CAP) { s_val[p] = (v).y / T; s_idx[p] = bi + 1; } } \
        if (t2 > THT) { int p = atomicAdd(&s_cnt, 1); if (p < CAP) { s_val[p] = (v).z / T; s_idx[p] = bi + 2; } } \
        if (t3 > THT) { int p = atomicAdd(&s_cnt, 1); if (p < CAP) { s_val[p] = (v).w / T; s_idx[p] = bi + 3; } } \
    }

__global__ __launch_bounds__(NT, 8) void dream_row_kernel(
    const float* __restrict__ logits,
    const float* __restrict__ gumbel,
    const float* __restrict__ tempP,
    const float* __restrict__ toppP,
    const int*   __restrict__ topkP,
    float* __restrict__ out_conf,
    float* __restrict__ out_x0,
    float* __restrict__ out_iconf)
{
    const int row = blockIdx.x;
    const int tid = threadIdx.x;
    const int lane = tid & 63;
    const int wid  = tid >> 6;
    const size_t base = (size_t)row * VOCAB;
    const vf4* l4 = (const vf4*)(logits + base);
    const float T = tempP[0];
    const float a = (1.0f / T) * LOG2E;
    const float b = -(KREF * LOG2E);

    __shared__ float s_val[CAP];   // exact x = v/T for candidates
    __shared__ int   s_idx[CAP];
    __shared__ int   s_cnt;
    __shared__ float wsum[NWAVES], wmax[NWAVES];
    __shared__ float sh_S, sh_m;
    __shared__ float so_val[KMAX];
    __shared__ int   so_idx[KMAX];
    __shared__ int   sh_nk;
    __shared__ float sh_skept;

    if (tid == 0) s_cnt = 0;
    __syncthreads();

    // ---- streaming pass: this wave's CONTIGUOUS quarter, 8-deep nt batches ----
    float sA = 0.0f, sB = 0.0f;
    float tmax = -FLT_MAX;
    const int q  = wid * QUART;              // quarter start (float4 units)
    const int nk = (wid == 3) ? 29 : 32;     // 1KB chunks in this quarter

    int k = 0;
    #pragma unroll 1
    for (; k + 8 <= nk; k += 8) {
        vf4 r0 = __builtin_nontemporal_load(&l4[q + (k + 0) * 64 + lane]);
        vf4 r1 = __builtin_nontemporal_load(&l4[q + (k + 1) * 64 + lane]);
        vf4 r2 = __builtin_nontemporal_load(&l4[q + (k + 2) * 64 + lane]);
        vf4 r3 = __builtin_nontemporal_load(&l4[q + (k + 3) * 64 + lane]);
        vf4 r4 = __builtin_nontemporal_load(&l4[q + (k + 4) * 64 + lane]);
        vf4 r5 = __builtin_nontemporal_load(&l4[q + (k + 5) * 64 + lane]);
        vf4 r6 = __builtin_nontemporal_load(&l4[q + (k + 6) * 64 + lane]);
        vf4 r7 = __builtin_nontemporal_load(&l4[q + (k + 7) * 64 + lane]);
        PROCESS(r0, q + (k + 0) * 64 + lane);
        PROCESS(r1, q + (k + 1) * 64 + lane);
        PROCESS(r2, q + (k + 2) * 64 + lane);
        PROCESS(r3, q + (k + 3) * 64 + lane);
        PROCESS(r4, q + (k + 4) * 64 + lane);
        PROCESS(r5, q + (k + 5) * 64 + lane);
        PROCESS(r6, q + (k + 6) * 64 + lane);
        PROCESS(r7, q + (k + 7) * 64 + lane);
    }
    #pragma unroll 1
    for (; k < nk; ++k) {                    // w=3 only: 5 single chunks
        vf4 v = __builtin_nontemporal_load(&l4[q + k * 64 + lane]);
        PROCESS(v, q + k * 64 + lane);
    }

    // ---- wave-shuffle reduce, then tiny cross-wave combine ----
    float s = sA + sB;
    float mx = tmax;
    #pragma unroll
    for (int o = 32; o > 0; o >>= 1) {
        s  += __shfl_down(s, o, 64);
        mx  = fmaxf(mx, __shfl_down(mx, o, 64));
    }
    if (lane == 0) { wsum[wid] = s; wmax[wid] = mx; }
    __syncthreads();
    if (tid == 0) {
        float St = 0.0f, Mt = -FLT_MAX;
        #pragma unroll
        for (int w = 0; w < NWAVES; ++w) { St += wsum[w]; Mt = fmaxf(Mt, wmax[w]); }
        sh_S = St; sh_m = Mt;
    }
    __syncthreads();
    const float S_K = sh_S;
    const float m_t = sh_m;
    int C = min(s_cnt, CAP);

    // ---- rare fallback: fixed theta missed — recollect with adaptive theta ----
    if (C < KMAX) {
        if (tid == 0) s_cnt = 0;
        __syncthreads();
        const float th2t = m_t - FBDELTA;
        for (int j = tid; j < NCHUNK; j += NT) {
            vf4 v = __builtin_nontemporal_load(&l4[j]);
            float t0 = fmaf(v.x, a, b);
            float t1 = fmaf(v.y, a, b);
            float t2 = fmaf(v.z, a, b);
            float t3 = fmaf(v.w, a, b);
            int bi = j * 4;
            if (t0 > th2t) { int p = atomicAdd(&s_cnt, 1); if (p < CAP) { s_val[p] = v.x / T; s_idx[p] = bi;     } }
            if (t1 > th2t) { int p = atomicAdd(&s_cnt, 1); if (p < CAP) { s_val[p] = v.y / T; s_idx[p] = bi + 1; } }
            if (t2 > th2t) { int p = atomicAdd(&s_cnt, 1); if (p < CAP) { s_val[p] = v.z / T; s_idx[p] = bi + 2; } }
            if (t3 > th2t) { int p = atomicAdd(&s_cnt, 1); if (p < CAP) { s_val[p] = v.w / T; s_idx[p] = bi + 3; } }
        }
        __syncthreads();
        C = min(s_cnt, CAP);
    }

    // ---- rank candidates on exact x (stable: value desc, index asc); keep top-KMAX ----
    for (int c = tid; c < C; c += NT) {
        float vc = s_val[c]; int ic = s_idx[c];
        int r = 0;
        #pragma unroll 4
        for (int j = 0; j < C; ++j) {
            float vj = s_val[j];
            if (vj > vc || (vj == vc && s_idx[j] < ic)) r++;
        }
        if (r < KMAX) { so_val[r] = vc; so_idx[r] = ic; }
    }
    __syncthreads();

    // ---- top-p prefix walk + top-k cap; replicate reference addition order ----
    if (tid == 0) {
        int k2 = topkP[0]; if (k2 > KMAX) k2 = KMAX; if (k2 < 1) k2 = 1;
        const float topp = toppP[0];
        const int lim = min(C, k2);
        float cum = 0.0f;
        float skept = 0.0f;
        int nk2 = 0;
        for (int j = 0; j < lim; ++j) {
            if (cum > topp) break;
            float e = exp2f(fmaf(so_val[j], LOG2E, b));
            cum += e / S_K;
            skept += e;
            nk2++;
        }
        sh_nk = nk2;
        sh_skept = skept;
    }
    __syncthreads();
    const int nkk = sh_nk;
    const float skept = sh_skept;

    // ---- Gumbel argmax over kept tokens (wave 0 only; first-index tie-break) ----
    if (wid == 0) {
        float bv = -FLT_MAX; int bi = 0x7FFFFFFF; float bx = 0.0f;
        if (lane < nkk) {
            int gi = so_idx[lane];
            bx = so_val[lane];
            bv = bx + gumbel[base + gi];
            bi = gi;
        }
        #pragma unroll
        for (int o = 32; o > 0; o >>= 1) {
            float ov = __shfl_down(bv, o, 64);
            int   oi = __shfl_down(bi, o, 64);
            float ox = __shfl_down(bx, o, 64);
            if (ov > bv || (ov == bv && oi < bi)) { bv = ov; bi = oi; bx = ox; }
        }
        if (lane == 0) {
            float eb = exp2f(fmaf(bx, LOG2E, b));
            float confv = eb / skept;
            out_conf[row]  = confv;
            out_x0[row]    = (float)bi;
            out_iconf[row] = confv;
        }
    }
}

// Global accept step: any(conf > thr) ? per-row high : one-hot at argmax(conf)
__global__ __launch_bounds__(NT) void accept_kernel(
    const float* __restrict__ conf,
    const float* __restrict__ thrP,
    float* __restrict__ acc_out,
    int N)
{
    __shared__ float rv[NT];
    __shared__ int   ri[NT];
    __shared__ int   ra[NT];
    const int tid = threadIdx.x;
    const float thr = thrP[0];

    float bv = -FLT_MAX; int bi = 0x7FFFFFFF; int any = 0;
    for (int i = tid; i < N; i += NT) {
        float v = conf[i];
        if (v > thr) any = 1;
        if (v > bv) { bv = v; bi = i; }
    }
    rv[tid] = bv; ri[tid] = bi; ra[tid] = any;
    __syncthreads();
    #pragma unroll
    for (int s = NT / 2; s > 0; s >>= 1) {
        if (tid < s) {
            float ov = rv[tid + s]; int oi = ri[tid + s];
            if (ov > rv[tid] || (ov == rv[tid] && oi < ri[tid])) {
                rv[tid] = ov; ri[tid] = oi;
            }
            ra[tid] |= ra[tid + s];
        }
        __syncthreads();
    }
    const int anyHigh = ra[0];
    const int amax = ri[0];
    for (int i = tid; i < N; i += NT) {
        float a;
        if (anyHigh) a = (conf[i] > thr) ? 1.0f : 0.0f;
        else         a = (i == amax) ? 1.0f : 0.0f;
        acc_out[i] = a;
    }
}

extern "C" void kernel_launch(void* const* d_in, const int* in_sizes, int n_in,
                              void* d_out, int out_size, void* d_ws, size_t ws_size,
                              hipStream_t stream)
{
    const float* logits = (const float*)d_in[0];
    const float* gumbel = (const float*)d_in[1];
    const float* tempP  = (const float*)d_in[2];
    const float* toppP  = (const float*)d_in[3];
    const int*   topkP  = (const int*)d_in[4];
    const float* thrP   = (const float*)d_in[5];
    float* out = (float*)d_out;
    const int N = in_sizes[0] / VOCAB;

    dream_row_kernel<<<N, NT, 0, stream>>>(
        logits, gumbel, tempP, toppP, topkP,
        out /*confidence*/, out + N /*x0*/, out + 2 * N /*initial_confidence*/);

    accept_kernel<<<1, NT, 0, stream>>>(
        out, thrP, out + 3 * N /*accepted*/, N);
}